// Round 3
// baseline (191.843 us; speedup 1.0000x reference)
//
#include <hip/hip_runtime.h>
#include <math.h>

#define D 128
#define L 50
#define SCALE 0.08838834764831845f   // 1/sqrt(128)

using bf16x8 = __attribute__((ext_vector_type(8))) short;   // MFMA A/B frag
using f32x4  = __attribute__((ext_vector_type(4))) float;   // MFMA C/D frag

union FragU { bf16x8 f; uint2 u2[2]; uint4 u4; };

// ---- bf16 pack/unpack helpers (RNE) ---------------------------------------
__device__ __forceinline__ unsigned f2bf(float x) {
    union { float f; unsigned u; } v; v.f = x;
    return (v.u + 0x7fffu + ((v.u >> 16) & 1u)) >> 16;
}
__device__ __forceinline__ float bflo(unsigned u) {
    union { unsigned u; float f; } v; v.u = u << 16; return v.f;
}
__device__ __forceinline__ float bfhi(unsigned u) {
    union { unsigned u; float f; } v; v.u = u & 0xffff0000u; return v.f;
}

// ---------------------------------------------------------------------------
// prep_all (614 blocks x 256)  — unchanged.
// ---------------------------------------------------------------------------
__global__ __launch_bounds__(256) void prep_all_kernel(
    const float* __restrict__ Wu, const float* __restrict__ Wi,
    const float* __restrict__ ue, const float* __restrict__ ie,
    const float* __restrict__ gu, const float* __restrict__ gi,
    const float* __restrict__ uu, const float* __restrict__ ui,
    const float* __restrict__ uek, const float* __restrict__ iek,
    unsigned short* __restrict__ Bptu, unsigned short* __restrict__ Bpti,
    unsigned short* __restrict__ Btu, unsigned short* __restrict__ Bti)
{
    __shared__ float T[2][128];                    // only used by EKGU blocks
    int b = blockIdx.x, t = threadIdx.x;
    if (b < 50) {
        int side = b / 25;
        int o = (b % 25) * 256 + t;                 // < 6400
        int d = o / L, l = o % L;
        const float* W = side ? Wi : Wu;
        const float* E = side ? ie : ue;
        unsigned short* Bpt = side ? Bpti : Bptu;
        float a = 0.f;
        for (int k = 0; k < D; ++k) a += W[d * D + k] * E[l * D + k];
        Bpt[(128 + l) * 128 + d] = (unsigned short)f2bf(a);
    } else if (b < 306) {
        int bb = b - 50;
        int side = bb / 128;
        int o = (bb % 128) * 256 + t;               // < 32768
        int r = o >> 7, c = o & 127;                // r 0..255 (GU: 256 rows)
        const float* G = side ? gi : gu;
        const float* U = side ? ui : uu;
        unsigned short* Bt = side ? Bti : Btu;
        float a = 0.f;
        for (int k = 0; k < D; ++k) a += G[r * D + k] * U[k * D + c];
        Bt[c * 448 + r] = (unsigned short)f2bf(a);
    } else if (b < 434) {
        int bb = b - 306;
        int side = bb >> 6;                         // 64 blocks/side
        int o = (bb & 63) * 256 + t;                // < 16384
        int r = o >> 7, c = o & 127;                // r 0..127 (upd_bot)
        const float* U = side ? ui : uu;
        unsigned short* Bt = side ? Bti : Btu;
        Bt[c * 448 + 320 + r] = (unsigned short)f2bf(U[(128 + r) * D + c]);
        if (r < 14) Bt[c * 448 + 306 + r] = 0;
    } else if (b < 562) {
        int bb = b - 434;
        int side = bb >> 6;
        int o = (bb & 63) * 256 + t;                // < 16384
        int k = o >> 7, c = o & 127;
        const float* W = side ? Wi : Wu;
        unsigned short* Bpt = side ? Bpti : Bptu;
        Bpt[c * 128 + k] = (unsigned short)f2bf(W[k * D + c]);
    } else if (b < 564) {
        int side = b - 562;
        unsigned short* Bpt = side ? Bpti : Bptu;
        for (int j = 0; j < 7; ++j)
            Bpt[178 * 128 + t * 7 + j] = 0;
    } else {
        int bb = b - 564;
        int side = bb / 25;
        int ro = (bb % 25) * 2;                     // 2 embk rows per block
        const float* EK = side ? iek : uek;
        const float* G  = side ? gi : gu;
        const float* U  = side ? ui : uu;
        unsigned short* Bt = side ? Bti : Btu;
        int r = t >> 7, c = t & 127;
        float a = 0.f;
        for (int k = 0; k < D; ++k) a += EK[(ro + r) * D + k] * G[k * D + c];
        T[r][c] = a;
        __syncthreads();
        float e = 0.f;
        for (int j = 0; j < D; ++j) e += T[r][j] * U[j * D + c];
        Bt[c * 448 + 256 + ro + r] = (unsigned short)f2bf(e);
    }
}

// ---------------------------------------------------------------------------
// proj_mfma — unchanged.
// ---------------------------------------------------------------------------
__global__ __launch_bounds__(256) void proj_mfma(
    const float* __restrict__ Xu, const float* __restrict__ Xi,
    const unsigned* __restrict__ Bptu32, const unsigned* __restrict__ Bpti32,
    unsigned* __restrict__ h32, float* __restrict__ eproj,
    unsigned* __restrict__ A32, int NU)
{
    __shared__ __align__(16) unsigned Bs[192 * 68];     // 52 KB
    int t = threadIdx.x;
    int nb = blockIdx.x * 32;
    const float* X = (nb < NU) ? Xu : Xi;
    int xoff = (nb < NU) ? 0 : NU;
    const unsigned* Bt = (nb < NU) ? Bptu32 : Bpti32;   // [192][64 u32]
    int wave = t >> 6, lane = t & 63;
    int m16 = lane & 15, quad = lane >> 4;

    #pragma unroll
    for (int i = 0; i < 12; ++i) {                      // 3072 uint4
        int idx = t + i * 256;
        int c = idx >> 4, q = idx & 15;
        uint4 v = *(const uint4*)&Bt[(size_t)c * 64 + q * 4];
        *(uint4*)&Bs[c * 68 + q * 4] = v;
    }
    __syncthreads();

    f32x4 acc[2][3];
    for (int i = 0; i < 2; ++i)
        for (int j = 0; j < 3; ++j) acc[i][j] = (f32x4){0.f, 0.f, 0.f, 0.f};

    #pragma unroll
    for (int kc = 0; kc < 4; ++kc) {
        FragU a[2];
        #pragma unroll
        for (int mi = 0; mi < 2; ++mi) {
            int row = nb + mi * 16 + m16;
            const float* src = &X[(size_t)(row - xoff) * D + kc * 32 + quad * 8];
            float4 v0 = *(const float4*)&src[0];
            float4 v1 = *(const float4*)&src[4];
            uint4 pk;
            pk.x = f2bf(v0.x) | (f2bf(v0.y) << 16);
            pk.y = f2bf(v0.z) | (f2bf(v0.w) << 16);
            pk.z = f2bf(v1.x) | (f2bf(v1.y) << 16);
            pk.w = f2bf(v1.z) | (f2bf(v1.w) << 16);
            a[mi].u4 = pk;
            if (wave == 0)                              // one wave writes x->A32
                *(uint4*)&A32[(size_t)row * 224 + 160 + kc * 16 + quad * 4] = pk;
        }
        #pragma unroll
        for (int ni = 0; ni < 3; ++ni) {
            bf16x8 bb = *(const bf16x8*)&Bs[(wave * 48 + ni * 16 + m16) * 68 + kc * 16 + quad * 4];
            acc[0][ni] = __builtin_amdgcn_mfma_f32_16x16x32_bf16(a[0].f, bb, acc[0][ni], 0, 0, 0);
            acc[1][ni] = __builtin_amdgcn_mfma_f32_16x16x32_bf16(a[1].f, bb, acc[1][ni], 0, 0, 0);
        }
    }
    // epilogue: C/D layout col=lane&15, row=quad*4+r
    #pragma unroll
    for (int mi = 0; mi < 2; ++mi)
        #pragma unroll
        for (int ni = 0; ni < 3; ++ni) {
            int col = wave * 48 + ni * 16 + m16;
            #pragma unroll
            for (int r = 0; r < 4; ++r) {
                float me = acc[mi][ni][r];
                float pr = __shfl_xor(me, 1);           // partner col (lane^1)
                int row = nb + mi * 16 + quad * 4 + r;
                if (col < 128) {
                    if (!(lane & 1))
                        h32[(size_t)row * 64 + (col >> 1)] = f2bf(me) | (f2bf(pr) << 16);
                } else if (col < 178) {
                    eproj[(size_t)row * L + (col - 128)] = me;
                }
            }
        }
}

// ---------------------------------------------------------------------------
// agg v3: 1 node / 256 threads (4 waves). Mail staged TWICE:
//   smrow [50][68]u32  row-major  -> score-phase A-frags (as in R7)
//   sT    [128][56]u16 transposed -> weighted-sum B-frags via ds_read_b128
// sT phys-row swizzle: phys = d ^ ((d>>3)&7)  (bijective; spreads the u16
// scatter writes to ~4-way instead of 32-way). Columns l=50..55 zeroed so
// the K=64 MFMA (alpha=0 there) never multiplies uninitialized LDS.
// Weighted sum: D = A(2x64 alpha bf16) x B(64x16 mailT block) per wave/ni.
// ---------------------------------------------------------------------------
__global__ __launch_bounds__(256) void agg_kernel(
    const unsigned* __restrict__ h32, const float* __restrict__ eproj,
    const int* __restrict__ unbr, const int* __restrict__ untime,
    const int* __restrict__ inbr, const int* __restrict__ intime,
    unsigned* __restrict__ A32, int NU, int NI)
{
    __shared__ __align__(16) unsigned smrow[50 * 68];            // 13600 B
    __shared__ __align__(16) unsigned short sT[128 * 56 + 16];   // 14368 B
    __shared__ __align__(16) unsigned shb[64];                   // h bf16 pairs
    __shared__ __align__(16) unsigned salb[64];                  // alpha bf16 pairs: [0:31] long, [32:63] short
    __shared__ float se2[2][64];                                 // [long/short][l]
    __shared__ __align__(16) int stime[52];
    __shared__ int sreorder[50], snbr[50], slast;

    int t = threadIdx.x;
    int g = blockIdx.x;
    int wv = t >> 6, lane = t & 63;
    int m16 = lane & 15, quad = lane >> 4;

    const unsigned* mail; const int* nbrp; const int* timp;
    if (g < NU) { mail = h32 + (size_t)NU * 64; nbrp = unbr + (size_t)g * L;        timp = untime + (size_t)g * L; }
    else        { mail = h32;                   nbrp = inbr + (size_t)(g - NU) * L; timp = intime + (size_t)(g - NU) * L; }

    if (t < 64) shb[t] = h32[(size_t)g * 64 + t];
    if (t < L) { stime[t] = timp[t]; snbr[t] = nbrp[t]; }
    __syncthreads();

    // ---- issue mailbox gather early (L2 latency hides under rank loop) ----
    // 800 uint4 chunks: c = t + 256p; r = c>>4 (mail row), q = c&15 (16B chunk)
    uint4 vbuf[4];
    #pragma unroll
    for (int p = 0; p < 4; ++p) {
        int c = t + p * 256;
        if (c < 800) {
            int r = c >> 4, q = c & 15;
            vbuf[p] = *(const uint4*)&mail[(size_t)snbr[r] * 64 + q * 4];
        }
    }

    // ---- ranks (stable argsort∘argsort) + first-occurrence argmax ---------
    if (t < L) {
        int ti = stime[t];
        int rank = 0, bad = 0;          // bad: exists j beating t for argmax
        #pragma unroll
        for (int j4 = 0; j4 < 48; j4 += 4) {
            int4 v = *(const int4*)&stime[j4];
            int tj;
            tj = v.x; rank += (tj < ti) || (tj == ti && (j4 + 0) < t); bad |= (tj > ti) || (tj == ti && (j4 + 0) < t);
            tj = v.y; rank += (tj < ti) || (tj == ti && (j4 + 1) < t); bad |= (tj > ti) || (tj == ti && (j4 + 1) < t);
            tj = v.z; rank += (tj < ti) || (tj == ti && (j4 + 2) < t); bad |= (tj > ti) || (tj == ti && (j4 + 2) < t);
            tj = v.w; rank += (tj < ti) || (tj == ti && (j4 + 3) < t); bad |= (tj > ti) || (tj == ti && (j4 + 3) < t);
        }
        {
            int2 v = *(const int2*)&stime[48];
            int tj;
            tj = v.x; rank += (tj < ti) || (tj == ti && 48 < t); bad |= (tj > ti) || (tj == ti && 48 < t);
            tj = v.y; rank += (tj < ti) || (tj == ti && 49 < t); bad |= (tj > ti) || (tj == ti && 49 < t);
        }
        sreorder[t] = L - 1 - rank;
        if (!bad) slast = t;
    }

    // ---- stage: row-major copy + transposed copy (phys-row swizzle) -------
    #pragma unroll
    for (int p = 0; p < 4; ++p) {
        int c = t + p * 256;
        if (c < 800) {
            int r = c >> 4, q = c & 15;
            uint4 v = vbuf[p];
            *(uint4*)&smrow[r * 68 + q * 4] = v;
            // logical d = q*8 + j -> phys row = q*8 + (j ^ (q&7))
            int rowbase = q * 8, xq = q & 7;
            sT[(rowbase + (0 ^ xq)) * 56 + r] = (unsigned short)(v.x & 0xffff);
            sT[(rowbase + (1 ^ xq)) * 56 + r] = (unsigned short)(v.x >> 16);
            sT[(rowbase + (2 ^ xq)) * 56 + r] = (unsigned short)(v.y & 0xffff);
            sT[(rowbase + (3 ^ xq)) * 56 + r] = (unsigned short)(v.y >> 16);
            sT[(rowbase + (4 ^ xq)) * 56 + r] = (unsigned short)(v.z & 0xffff);
            sT[(rowbase + (5 ^ xq)) * 56 + r] = (unsigned short)(v.z >> 16);
            sT[(rowbase + (6 ^ xq)) * 56 + r] = (unsigned short)(v.w & 0xffff);
            sT[(rowbase + (7 ^ xq)) * 56 + r] = (unsigned short)(v.w >> 16);
        }
    }
    // zero columns l=50..55 (all 128 rows) + tail pad
    if (t >= 144 && t < 240) {
        int idx = t - 144;                  // 0..95
        int r = 50 + (idx >> 4), q = idx & 15;
        #pragma unroll
        for (int j = 0; j < 8; ++j) sT[(q * 8 + j) * 56 + r] = 0;
    }
    if (t < 16) sT[128 * 56 + t] = 0;
    __syncthreads();

    // ---- scores via MFMA: 4 waves x 16 l-rows; col0 = mail.h, col1 = mail.last
    {
        int s = wv * 16 + m16; if (s > 49) s = 49;
        int last = slast;
        f32x4 dd = {0.f, 0.f, 0.f, 0.f};
        #pragma unroll
        for (int kc = 0; kc < 4; ++kc) {
            FragU af, bf_;
            af.u4 = *(const uint4*)&smrow[s * 68 + kc * 16 + quad * 4];
            if (m16 == 1) bf_.u4 = *(const uint4*)&smrow[last * 68 + kc * 16 + quad * 4];
            else          bf_.u4 = *(const uint4*)&shb[kc * 16 + quad * 4];
            dd = __builtin_amdgcn_mfma_f32_16x16x32_bf16(af.f, bf_.f, dd, 0, 0, 0);
        }
        if (m16 < 2) {                      // C/D: row=quad*4+r, col=m16
            #pragma unroll
            for (int r = 0; r < 4; ++r)
                se2[m16][wv * 16 + quad * 4 + r] = dd[r];
        }
    }
    __syncthreads();

    // ---- softmax (waves 0,1) + bf16 alpha pack ----------------------------
    if (wv < 2) {
        float sc = -1e30f;
        if (lane < L) {
            sc = (wv == 0)
               ? (se2[0][lane] + eproj[(size_t)g * L + sreorder[lane]]) * SCALE
               : se2[1][lane] * SCALE;
        }
        float mx = sc;
        for (int off = 32; off; off >>= 1) mx = fmaxf(mx, __shfl_xor(mx, off));
        float ex = (lane < L) ? expf(sc - mx) : 0.f;
        float sm = ex;
        for (int off = 32; off; off >>= 1) sm += __shfl_xor(sm, off);
        float al = ex / sm;                 // 0 for lane>=50
        float alo = __shfl_xor(al, 1);
        if (!(lane & 1))
            salb[wv * 32 + (lane >> 1)] = f2bf(al) | (f2bf(alo) << 16);
    }
    if (t >= 128 && t < 160) A32[(size_t)g * 224 + 128 + (t - 128)] = 0u;
    __syncthreads();

    // ---- weighted sums via MFMA: A = [alpha_long; alpha_short] (bf16),
    //      B = mailT rows (l-major) via plain ds_read_b128 ------------------
    {
        FragU a0, a1;
        int arow = (m16 & 1) * 32;          // row0=long, row1=short (rows>=2 junk)
        a0.u4 = *(const uint4*)&salb[arow + quad * 4];        // k 0..31
        a1.u4 = *(const uint4*)&salb[arow + 16 + quad * 4];   // k 32..63
        unsigned short* Au = (unsigned short*)A32 + (size_t)g * 448;
        #pragma unroll
        for (int ni = 0; ni < 2; ++ni) {
            int dblk = wv * 2 + ni;         // 8 d-blocks over 4 waves
            int d = dblk * 16 + m16;
            int phys = d ^ ((d >> 3) & 7);
            const unsigned short* rowp = &sT[phys * 56];
            FragU fb0, fb1;
            fb0.u4 = *(const uint4*)&rowp[quad * 8];          // l = quad*8 + j
            fb1.u4 = *(const uint4*)&rowp[32 + quad * 8];     // l = 32 + quad*8 + j
            f32x4 acc = {0.f, 0.f, 0.f, 0.f};
            acc = __builtin_amdgcn_mfma_f32_16x16x32_bf16(a0.f, fb0.f, acc, 0, 0, 0);
            acc = __builtin_amdgcn_mfma_f32_16x16x32_bf16(a1.f, fb1.f, acc, 0, 0, 0);
            if (quad == 0) {                // D rows 0 (long) / 1 (short)
                Au[dblk * 16 + m16]       = (unsigned short)f2bf(acc[0]);
                Au[128 + dblk * 16 + m16] = (unsigned short)f2bf(acc[1]);
            }
        }
    }
    // alpha scatter (bf16 straight from the packed A-operand row 0 = long)
    if (t < L)
        ((unsigned short*)A32)[(size_t)g * 448 + 256 + sreorder[t]] =
            ((const unsigned short*)&salb[0])[t];
}

// ---------------------------------------------------------------------------
// gemm_out v2 — unchanged.
// ---------------------------------------------------------------------------
__global__ __launch_bounds__(256) void gemm_out_mfma(
    const unsigned* __restrict__ A32,
    const unsigned* __restrict__ Btu32, const unsigned* __restrict__ Bti32,
    float* __restrict__ out, int NU)
{
    __shared__ __align__(16) unsigned Bs[64 * 228];     // 57 KB
    int t = threadIdx.x;
    int rowblk = blockIdx.x >> 1, half = blockIdx.x & 1;
    int nb = rowblk * 128;
    const unsigned* Bt = (nb < NU) ? Btu32 : Bti32;     // [128 n][224 u32]
    int wave = t >> 6, lane = t & 63;
    int m16 = lane & 15, quad = lane >> 4;

    #pragma unroll
    for (int i = 0; i < 14; ++i) {                      // 3584 uint4
        int idx = t + i * 256;
        int n = idx / 56, q = idx - n * 56;             // 56 uint4 per row
        uint4 v = *(const uint4*)&Bt[(size_t)(half * 64 + n) * 224 + q * 4];
        *(uint4*)&Bs[n * 228 + q * 4] = v;
    }
    __syncthreads();

    #pragma unroll
    for (int j = 0; j < 2; ++j) {
        int mrow0 = nb + (wave * 2 + j) * 16;
        f32x4 acc[4] = {{0.f,0.f,0.f,0.f},{0.f,0.f,0.f,0.f},
                        {0.f,0.f,0.f,0.f},{0.f,0.f,0.f,0.f}};
        for (int kc = 0; kc < 14; ++kc) {
            FragU af;
            af.u4 = *(const uint4*)&A32[(size_t)(mrow0 + m16) * 224 + kc * 16 + quad * 4];
            #pragma unroll
            for (int ni = 0; ni < 4; ++ni) {
                bf16x8 bf = *(const bf16x8*)&Bs[(ni * 16 + m16) * 228 + kc * 16 + quad * 4];
                acc[ni] = __builtin_amdgcn_mfma_f32_16x16x32_bf16(af.f, bf, acc[ni], 0, 0, 0);
            }
        }
        #pragma unroll
        for (int ni = 0; ni < 4; ++ni)
            #pragma unroll
            for (int r = 0; r < 4; ++r) {
                int row = mrow0 + quad * 4 + r;
                int col = half * 64 + ni * 16 + m16;
                out[(size_t)row * D + col] = tanhf(acc[ni][r]);
            }
    }
}

// ---------------------------------------------------------------------------
extern "C" void kernel_launch(void* const* d_in, const int* in_sizes, int n_in,
                              void* d_out, int out_size, void* d_ws, size_t ws_size,
                              hipStream_t stream) {
    const float* user   = (const float*)d_in[0];
    const float* item   = (const float*)d_in[1];
    const float* Wu     = (const float*)d_in[2];
    const float* Wi     = (const float*)d_in[3];
    const float* gate_u = (const float*)d_in[4];
    const float* gate_i = (const float*)d_in[5];
    const float* upd_u  = (const float*)d_in[6];
    const float* upd_i  = (const float*)d_in[7];
    const float* uemb   = (const float*)d_in[8];
    const float* uembk  = (const float*)d_in[9];
    const float* iemb   = (const float*)d_in[10];
    const float* iembk  = (const float*)d_in[11];
    const int*   unbr   = (const int*)d_in[12];
    const int*   untime = (const int*)d_in[13];
    const int*   inbr   = (const int*)d_in[14];
    const int*   intime = (const int*)d_in[15];

    int NU = in_sizes[0] / D;
    int NI = in_sizes[1] / D;
    int N  = NU + NI;

    float* eproj  = (float*)d_ws;                   // N*50 f32
    unsigned* h32   = (unsigned*)(eproj + (size_t)N * L);  // N*64 u32
    unsigned* A32   = h32 + (size_t)N * 64;         // N*224 u32 (bf16 A)
    unsigned* Btu32 = A32 + (size_t)N * 224;        // 128*224 u32 each
    unsigned* Bti32 = Btu32 + 128 * 224;
    unsigned* Bptu32 = Bti32 + 128 * 224;           // 192*64 u32 each
    unsigned* Bpti32 = Bptu32 + 192 * 64;

    prep_all_kernel<<<614, 256, 0, stream>>>(Wu, Wi, uemb, iemb, gate_u, gate_i,
                                             upd_u, upd_i, uembk, iembk,
                                             (unsigned short*)Bptu32,
                                             (unsigned short*)Bpti32,
                                             (unsigned short*)Btu32,
                                             (unsigned short*)Bti32);
    proj_mfma<<<N / 32, 256, 0, stream>>>(user, item, Bptu32, Bpti32,
                                          h32, eproj, A32, NU);
    agg_kernel<<<N, 256, 0, stream>>>(h32, eproj, unbr, untime, inbr,
                                      intime, A32, NU, NI);
    gemm_out_mfma<<<N / 64, 256, 0, stream>>>(A32, Btu32, Bti32,
                                              (float*)d_out, NU);
}

// Round 4
// 178.673 us; speedup vs baseline: 1.0737x; 1.0737x over previous
//
#include <hip/hip_runtime.h>
#include <math.h>

#define D 128
#define L 50
#define SCALE 0.08838834764831845f   // 1/sqrt(128)

using bf16x8 = __attribute__((ext_vector_type(8))) short;   // MFMA A/B frag
using f32x4  = __attribute__((ext_vector_type(4))) float;   // MFMA C/D frag

union FragU { bf16x8 f; uint2 u2[2]; uint4 u4; };

// ---- bf16 pack/unpack helpers (RNE) ---------------------------------------
__device__ __forceinline__ unsigned f2bf(float x) {
    union { float f; unsigned u; } v; v.f = x;
    return (v.u + 0x7fffu + ((v.u >> 16) & 1u)) >> 16;
}
__device__ __forceinline__ float bflo(unsigned u) {
    union { unsigned u; float f; } v; v.u = u << 16; return v.f;
}
__device__ __forceinline__ float bfhi(unsigned u) {
    union { unsigned u; float f; } v; v.u = u & 0xffff0000u; return v.f;
}

// ---------------------------------------------------------------------------
// prep_all (614 blocks x 256)  — unchanged.
// ---------------------------------------------------------------------------
__global__ __launch_bounds__(256) void prep_all_kernel(
    const float* __restrict__ Wu, const float* __restrict__ Wi,
    const float* __restrict__ ue, const float* __restrict__ ie,
    const float* __restrict__ gu, const float* __restrict__ gi,
    const float* __restrict__ uu, const float* __restrict__ ui,
    const float* __restrict__ uek, const float* __restrict__ iek,
    unsigned short* __restrict__ Bptu, unsigned short* __restrict__ Bpti,
    unsigned short* __restrict__ Btu, unsigned short* __restrict__ Bti)
{
    __shared__ float T[2][128];                    // only used by EKGU blocks
    int b = blockIdx.x, t = threadIdx.x;
    if (b < 50) {
        int side = b / 25;
        int o = (b % 25) * 256 + t;                 // < 6400
        int d = o / L, l = o % L;
        const float* W = side ? Wi : Wu;
        const float* E = side ? ie : ue;
        unsigned short* Bpt = side ? Bpti : Bptu;
        float a = 0.f;
        for (int k = 0; k < D; ++k) a += W[d * D + k] * E[l * D + k];
        Bpt[(128 + l) * 128 + d] = (unsigned short)f2bf(a);
    } else if (b < 306) {
        int bb = b - 50;
        int side = bb / 128;
        int o = (bb % 128) * 256 + t;               // < 32768
        int r = o >> 7, c = o & 127;                // r 0..255 (GU: 256 rows)
        const float* G = side ? gi : gu;
        const float* U = side ? ui : uu;
        unsigned short* Bt = side ? Bti : Btu;
        float a = 0.f;
        for (int k = 0; k < D; ++k) a += G[r * D + k] * U[k * D + c];
        Bt[c * 448 + r] = (unsigned short)f2bf(a);
    } else if (b < 434) {
        int bb = b - 306;
        int side = bb >> 6;                         // 64 blocks/side
        int o = (bb & 63) * 256 + t;                // < 16384
        int r = o >> 7, c = o & 127;                // r 0..127 (upd_bot)
        const float* U = side ? ui : uu;
        unsigned short* Bt = side ? Bti : Btu;
        Bt[c * 448 + 320 + r] = (unsigned short)f2bf(U[(128 + r) * D + c]);
        if (r < 14) Bt[c * 448 + 306 + r] = 0;
    } else if (b < 562) {
        int bb = b - 434;
        int side = bb >> 6;
        int o = (bb & 63) * 256 + t;                // < 16384
        int k = o >> 7, c = o & 127;
        const float* W = side ? Wi : Wu;
        unsigned short* Bpt = side ? Bpti : Bptu;
        Bpt[c * 128 + k] = (unsigned short)f2bf(W[k * D + c]);
    } else if (b < 564) {
        int side = b - 562;
        unsigned short* Bpt = side ? Bpti : Bptu;
        for (int j = 0; j < 7; ++j)
            Bpt[178 * 128 + t * 7 + j] = 0;
    } else {
        int bb = b - 564;
        int side = bb / 25;
        int ro = (bb % 25) * 2;                     // 2 embk rows per block
        const float* EK = side ? iek : uek;
        const float* G  = side ? gi : gu;
        const float* U  = side ? ui : uu;
        unsigned short* Bt = side ? Bti : Btu;
        int r = t >> 7, c = t & 127;
        float a = 0.f;
        for (int k = 0; k < D; ++k) a += EK[(ro + r) * D + k] * G[k * D + c];
        T[r][c] = a;
        __syncthreads();
        float e = 0.f;
        for (int j = 0; j < D; ++j) e += T[r][j] * U[j * D + c];
        Bt[c * 448 + 256 + ro + r] = (unsigned short)f2bf(e);
    }
}

// ---------------------------------------------------------------------------
// proj_mfma — unchanged.
// ---------------------------------------------------------------------------
__global__ __launch_bounds__(256) void proj_mfma(
    const float* __restrict__ Xu, const float* __restrict__ Xi,
    const unsigned* __restrict__ Bptu32, const unsigned* __restrict__ Bpti32,
    unsigned* __restrict__ h32, float* __restrict__ eproj,
    unsigned* __restrict__ A32, int NU)
{
    __shared__ __align__(16) unsigned Bs[192 * 68];     // 52 KB
    int t = threadIdx.x;
    int nb = blockIdx.x * 32;
    const float* X = (nb < NU) ? Xu : Xi;
    int xoff = (nb < NU) ? 0 : NU;
    const unsigned* Bt = (nb < NU) ? Bptu32 : Bpti32;   // [192][64 u32]
    int wave = t >> 6, lane = t & 63;
    int m16 = lane & 15, quad = lane >> 4;

    #pragma unroll
    for (int i = 0; i < 12; ++i) {                      // 3072 uint4
        int idx = t + i * 256;
        int c = idx >> 4, q = idx & 15;
        uint4 v = *(const uint4*)&Bt[(size_t)c * 64 + q * 4];
        *(uint4*)&Bs[c * 68 + q * 4] = v;
    }
    __syncthreads();

    f32x4 acc[2][3];
    for (int i = 0; i < 2; ++i)
        for (int j = 0; j < 3; ++j) acc[i][j] = (f32x4){0.f, 0.f, 0.f, 0.f};

    #pragma unroll
    for (int kc = 0; kc < 4; ++kc) {
        FragU a[2];
        #pragma unroll
        for (int mi = 0; mi < 2; ++mi) {
            int row = nb + mi * 16 + m16;
            const float* src = &X[(size_t)(row - xoff) * D + kc * 32 + quad * 8];
            float4 v0 = *(const float4*)&src[0];
            float4 v1 = *(const float4*)&src[4];
            uint4 pk;
            pk.x = f2bf(v0.x) | (f2bf(v0.y) << 16);
            pk.y = f2bf(v0.z) | (f2bf(v0.w) << 16);
            pk.z = f2bf(v1.x) | (f2bf(v1.y) << 16);
            pk.w = f2bf(v1.z) | (f2bf(v1.w) << 16);
            a[mi].u4 = pk;
            if (wave == 0)                              // one wave writes x->A32
                *(uint4*)&A32[(size_t)row * 224 + 160 + kc * 16 + quad * 4] = pk;
        }
        #pragma unroll
        for (int ni = 0; ni < 3; ++ni) {
            bf16x8 bb = *(const bf16x8*)&Bs[(wave * 48 + ni * 16 + m16) * 68 + kc * 16 + quad * 4];
            acc[0][ni] = __builtin_amdgcn_mfma_f32_16x16x32_bf16(a[0].f, bb, acc[0][ni], 0, 0, 0);
            acc[1][ni] = __builtin_amdgcn_mfma_f32_16x16x32_bf16(a[1].f, bb, acc[1][ni], 0, 0, 0);
        }
    }
    // epilogue: C/D layout col=lane&15, row=quad*4+r
    #pragma unroll
    for (int mi = 0; mi < 2; ++mi)
        #pragma unroll
        for (int ni = 0; ni < 3; ++ni) {
            int col = wave * 48 + ni * 16 + m16;
            #pragma unroll
            for (int r = 0; r < 4; ++r) {
                float me = acc[mi][ni][r];
                float pr = __shfl_xor(me, 1);           // partner col (lane^1)
                int row = nb + mi * 16 + quad * 4 + r;
                if (col < 128) {
                    if (!(lane & 1))
                        h32[(size_t)row * 64 + (col >> 1)] = f2bf(me) | (f2bf(pr) << 16);
                } else if (col < 178) {
                    eproj[(size_t)row * L + (col - 128)] = me;
                }
            }
        }
}

// ---------------------------------------------------------------------------
// agg — proven R7 version (2 nodes/block, VALU weighted sum).
// ---------------------------------------------------------------------------
__global__ __launch_bounds__(256) void agg_kernel(
    const unsigned* __restrict__ h32, const float* __restrict__ eproj,
    const int* __restrict__ unbr, const int* __restrict__ untime,
    const int* __restrict__ inbr, const int* __restrict__ intime,
    unsigned* __restrict__ A32, int NU, int NI)
{
    __shared__ unsigned smail[2][L * 66];     // bf16x2, stride 66 u32
    __shared__ unsigned shb[2][64];           // h packed bf16
    __shared__ float se2[2][2][64];           // [long/short][slot]
    __shared__ float salpha[2][L], salpha1[2][L];
    __shared__ int stime[2][L], sreorder[2][L], snbr[2][L], slast[2];

    int tb = threadIdx.x;
    int sub = tb >> 7;                  // node slot 0/1
    int t = tb & 127;                   // within-node tid
    int g = blockIdx.x * 2 + sub;       // global node
    int wave = t >> 6, lane = t & 63;
    int m16 = lane & 15, quad = lane >> 4;

    const unsigned* mail; const int* nbrp; const int* timp;
    if (g < NU) { mail = h32 + (size_t)NU * 64; nbrp = unbr + (size_t)g * L;        timp = untime + (size_t)g * L; }
    else        { mail = h32;                   nbrp = inbr + (size_t)(g - NU) * L; timp = intime + (size_t)(g - NU) * L; }

    if (t < 64) shb[sub][t] = h32[(size_t)g * 64 + t];
    if (t < L) { stime[sub][t] = timp[t]; snbr[sub][t] = nbrp[t]; }
    __syncthreads();

    // ranks (stable argsort∘argsort) + first-occurrence argmax
    if (t < L) {
        int ti = stime[sub][t]; int rank = 0; bool firstmax = true;
        for (int j = 0; j < L; ++j) {
            int tj = stime[sub][j];
            rank += (tj < ti) || (tj == ti && j < t);
            firstmax = firstmax && ((tj < ti) || (tj == ti && j >= t));
        }
        sreorder[sub][t] = L - 1 - rank;
        if (firstmax) slast[sub] = t;
    }
    // stage mail: uint2 global copy -> LDS stride 66 (no convert)
    {
        int q = t >> 5, p = t & 31;     // row group, pair index
        #pragma unroll
        for (int i = 0; i < 13; ++i) {
            int l = i * 4 + q;
            if (l < L) {
                uint2 v = *(const uint2*)&mail[(size_t)snbr[sub][l] * 64 + p * 2];
                *(uint2*)&smail[sub][l * 66 + 2 * p] = v;
            }
        }
    }
    __syncthreads();

    // scores via MFMA: col0 = mail.h (long), col1 = mail.last
    {
        const unsigned* bptr = (m16 == 1) ? &smail[sub][slast[sub] * 66]
                                          : &shb[sub][0];
        int s0 = wave * 32 + m16;  if (s0 > 49) s0 = 49;
        int s1 = wave * 32 + 16 + m16;  if (s1 > 49) s1 = 49;
        const unsigned* a0p = &smail[sub][s0 * 66];
        const unsigned* a1p = &smail[sub][s1 * 66];
        f32x4 d0 = {0.f, 0.f, 0.f, 0.f}, d1 = {0.f, 0.f, 0.f, 0.f};
        #pragma unroll
        for (int kc = 0; kc < 4; ++kc) {
            int off = kc * 16 + quad * 4;
            FragU bf_, af0, af1;
            bf_.u2[0] = *(const uint2*)&bptr[off];
            bf_.u2[1] = *(const uint2*)&bptr[off + 2];
            af0.u2[0] = *(const uint2*)&a0p[off];
            af0.u2[1] = *(const uint2*)&a0p[off + 2];
            af1.u2[0] = *(const uint2*)&a1p[off];
            af1.u2[1] = *(const uint2*)&a1p[off + 2];
            d0 = __builtin_amdgcn_mfma_f32_16x16x32_bf16(af0.f, bf_.f, d0, 0, 0, 0);
            d1 = __builtin_amdgcn_mfma_f32_16x16x32_bf16(af1.f, bf_.f, d1, 0, 0, 0);
        }
        if (m16 < 2) {                   // redistribute: row=quad*4+r, col=m16
            #pragma unroll
            for (int r = 0; r < 4; ++r) {
                se2[sub][m16][wave * 32 + quad * 4 + r]      = d0[r];
                se2[sub][m16][wave * 32 + 16 + quad * 4 + r] = d1[r];
            }
        }
    }
    __syncthreads();

    // softmax: wave0 long (+eproj), wave1 short
    float sc = -1e30f;
    if (lane < L) {
        sc = (wave == 0)
           ? (se2[sub][0][lane] + eproj[(size_t)g * L + sreorder[sub][lane]]) * SCALE
           : se2[sub][1][lane] * SCALE;
    }
    float mx = sc;
    for (int off = 32; off; off >>= 1) mx = fmaxf(mx, __shfl_xor(mx, off));
    float ex = (lane < L) ? expf(sc - mx) : 0.f;
    float sm = ex;
    for (int off = 32; off; off >>= 1) sm += __shfl_xor(sm, off);
    float al = ex / sm;
    if (lane < L) { if (wave == 0) salpha[sub][lane] = al; else salpha1[sub][lane] = al; }
    __syncthreads();

    // weighted sums: wave0 -> hl word lane, wave1 -> hs word lane (linear addr)
    {
        const float* alp = wave ? salpha1[sub] : salpha[sub];
        const unsigned* base = &smail[sub][lane];
        float ax = 0.f, ay = 0.f;
        for (int l = 0; l < L; ++l) {
            unsigned u = base[l * 66];
            float a = alp[l];
            ax += a * bflo(u);
            ay += a * bfhi(u);
        }
        A32[(size_t)g * 224 + wave * 64 + lane] = f2bf(ax) | (f2bf(ay) << 16);
    }
    if (t >= 64 && t < 96) A32[(size_t)g * 224 + 128 + (t - 64)] = 0u;
    __syncthreads();
    if (t < L) {
        ((unsigned short*)A32)[(size_t)g * 448 + 256 + sreorder[sub][t]] =
            (unsigned short)f2bf(salpha[sub][t]);
    }
}

// ---------------------------------------------------------------------------
// gemm_out v3: block = 128 rows x 32 cols (quarter). LDS 29.2 KB -> 5
// blocks/CU capacity; grid (N/128)*4 = 512 -> 2 resident blocks (8 waves)/CU.
// Bijective XCD-grouping swizzle keeps the 4 col-quarters of one row-block
// on the same XCD for A-panel L2 reuse. Requires gridDim.x % 8 == 0.
// ---------------------------------------------------------------------------
__global__ __launch_bounds__(256) void gemm_out_mfma(
    const unsigned* __restrict__ A32,
    const unsigned* __restrict__ Btu32, const unsigned* __restrict__ Bti32,
    float* __restrict__ out, int NU)
{
    __shared__ __align__(16) unsigned Bs[32 * 228];     // 29.2 KB
    int t = threadIdx.x;
    // bid -> (rowblk, quarter): quarters of a rowblk share an XCD
    int bid = blockIdx.x;
    int lid = bid >> 3, xcd = bid & 7;
    int idx = xcd * (gridDim.x >> 3) + lid;             // bijective
    int rowblk = idx >> 2, quarter = idx & 3;
    int nb = rowblk * 128;
    const unsigned* Bt = (nb < NU) ? Btu32 : Bti32;     // [128 n][224 u32]
    int wave = t >> 6, lane = t & 63;
    int m16 = lane & 15, quad = lane >> 4;

    #pragma unroll
    for (int i = 0; i < 7; ++i) {                       // 1792 uint4
        int idx2 = t + i * 256;
        int n = idx2 / 56, q = idx2 - n * 56;           // 56 uint4 per row
        uint4 v = *(const uint4*)&Bt[(size_t)(quarter * 32 + n) * 224 + q * 4];
        *(uint4*)&Bs[n * 228 + q * 4] = v;
    }
    __syncthreads();

    #pragma unroll
    for (int j = 0; j < 2; ++j) {
        int mrow0 = nb + (wave * 2 + j) * 16;
        f32x4 acc[2] = {{0.f,0.f,0.f,0.f},{0.f,0.f,0.f,0.f}};
        for (int kc = 0; kc < 14; ++kc) {
            FragU af;
            af.u4 = *(const uint4*)&A32[(size_t)(mrow0 + m16) * 224 + kc * 16 + quad * 4];
            #pragma unroll
            for (int ni = 0; ni < 2; ++ni) {
                bf16x8 bf = *(const bf16x8*)&Bs[(ni * 16 + m16) * 228 + kc * 16 + quad * 4];
                acc[ni] = __builtin_amdgcn_mfma_f32_16x16x32_bf16(af.f, bf, acc[ni], 0, 0, 0);
            }
        }
        #pragma unroll
        for (int ni = 0; ni < 2; ++ni)
            #pragma unroll
            for (int r = 0; r < 4; ++r) {
                int row = mrow0 + quad * 4 + r;
                int col = quarter * 32 + ni * 16 + m16;
                out[(size_t)row * D + col] = tanhf(acc[ni][r]);
            }
    }
}

// ---------------------------------------------------------------------------
extern "C" void kernel_launch(void* const* d_in, const int* in_sizes, int n_in,
                              void* d_out, int out_size, void* d_ws, size_t ws_size,
                              hipStream_t stream) {
    const float* user   = (const float*)d_in[0];
    const float* item   = (const float*)d_in[1];
    const float* Wu     = (const float*)d_in[2];
    const float* Wi     = (const float*)d_in[3];
    const float* gate_u = (const float*)d_in[4];
    const float* gate_i = (const float*)d_in[5];
    const float* upd_u  = (const float*)d_in[6];
    const float* upd_i  = (const float*)d_in[7];
    const float* uemb   = (const float*)d_in[8];
    const float* uembk  = (const float*)d_in[9];
    const float* iemb   = (const float*)d_in[10];
    const float* iembk  = (const float*)d_in[11];
    const int*   unbr   = (const int*)d_in[12];
    const int*   untime = (const int*)d_in[13];
    const int*   inbr   = (const int*)d_in[14];
    const int*   intime = (const int*)d_in[15];

    int NU = in_sizes[0] / D;
    int NI = in_sizes[1] / D;
    int N  = NU + NI;

    float* eproj  = (float*)d_ws;                   // N*50 f32
    unsigned* h32   = (unsigned*)(eproj + (size_t)N * L);  // N*64 u32
    unsigned* A32   = h32 + (size_t)N * 64;         // N*224 u32 (bf16 A)
    unsigned* Btu32 = A32 + (size_t)N * 224;        // 128*224 u32 each
    unsigned* Bti32 = Btu32 + 128 * 224;
    unsigned* Bptu32 = Bti32 + 128 * 224;           // 192*64 u32 each
    unsigned* Bpti32 = Bptu32 + 192 * 64;

    prep_all_kernel<<<614, 256, 0, stream>>>(Wu, Wi, uemb, iemb, gate_u, gate_i,
                                             upd_u, upd_i, uembk, iembk,
                                             (unsigned short*)Bptu32,
                                             (unsigned short*)Bpti32,
                                             (unsigned short*)Btu32,
                                             (unsigned short*)Bti32);
    proj_mfma<<<N / 32, 256, 0, stream>>>(user, item, Bptu32, Bpti32,
                                          h32, eproj, A32, NU);
    agg_kernel<<<N / 2, 256, 0, stream>>>(h32, eproj, unbr, untime, inbr,
                                          intime, A32, NU, NI);
    gemm_out_mfma<<<(N / 128) * 4, 256, 0, stream>>>(A32, Btu32, Bti32,
                                                     (float*)d_out, NU);
}

// Round 5
// 164.106 us; speedup vs baseline: 1.1690x; 1.0888x over previous
//
#include <hip/hip_runtime.h>
#include <math.h>

#define D 128
#define L 50
#define SCALE 0.08838834764831845f   // 1/sqrt(128)

using bf16x8 = __attribute__((ext_vector_type(8))) short;   // MFMA A/B frag
using f32x4  = __attribute__((ext_vector_type(4))) float;   // MFMA C/D frag

union FragU { bf16x8 f; uint2 u2[2]; uint4 u4; };

// ---- bf16 pack/unpack helpers (RNE) ---------------------------------------
__device__ __forceinline__ unsigned f2bf(float x) {
    union { float f; unsigned u; } v; v.f = x;
    return (v.u + 0x7fffu + ((v.u >> 16) & 1u)) >> 16;
}
__device__ __forceinline__ float bflo(unsigned u) {
    union { unsigned u; float f; } v; v.u = u << 16; return v.f;
}
__device__ __forceinline__ float bfhi(unsigned u) {
    union { unsigned u; float f; } v; v.u = u & 0xffff0000u; return v.f;
}

// ---------------------------------------------------------------------------
// prep_all (614 blocks x 256)  — unchanged.
// ---------------------------------------------------------------------------
__global__ __launch_bounds__(256) void prep_all_kernel(
    const float* __restrict__ Wu, const float* __restrict__ Wi,
    const float* __restrict__ ue, const float* __restrict__ ie,
    const float* __restrict__ gu, const float* __restrict__ gi,
    const float* __restrict__ uu, const float* __restrict__ ui,
    const float* __restrict__ uek, const float* __restrict__ iek,
    unsigned short* __restrict__ Bptu, unsigned short* __restrict__ Bpti,
    unsigned short* __restrict__ Btu, unsigned short* __restrict__ Bti)
{
    __shared__ float T[2][128];                    // only used by EKGU blocks
    int b = blockIdx.x, t = threadIdx.x;
    if (b < 50) {
        int side = b / 25;
        int o = (b % 25) * 256 + t;                 // < 6400
        int d = o / L, l = o % L;
        const float* W = side ? Wi : Wu;
        const float* E = side ? ie : ue;
        unsigned short* Bpt = side ? Bpti : Bptu;
        float a = 0.f;
        for (int k = 0; k < D; ++k) a += W[d * D + k] * E[l * D + k];
        Bpt[(128 + l) * 128 + d] = (unsigned short)f2bf(a);
    } else if (b < 306) {
        int bb = b - 50;
        int side = bb / 128;
        int o = (bb % 128) * 256 + t;               // < 32768
        int r = o >> 7, c = o & 127;                // r 0..255 (GU: 256 rows)
        const float* G = side ? gi : gu;
        const float* U = side ? ui : uu;
        unsigned short* Bt = side ? Bti : Btu;
        float a = 0.f;
        for (int k = 0; k < D; ++k) a += G[r * D + k] * U[k * D + c];
        Bt[c * 448 + r] = (unsigned short)f2bf(a);
    } else if (b < 434) {
        int bb = b - 306;
        int side = bb >> 6;                         // 64 blocks/side
        int o = (bb & 63) * 256 + t;                // < 16384
        int r = o >> 7, c = o & 127;                // r 0..127 (upd_bot)
        const float* U = side ? ui : uu;
        unsigned short* Bt = side ? Bti : Btu;
        Bt[c * 448 + 320 + r] = (unsigned short)f2bf(U[(128 + r) * D + c]);
        if (r < 14) Bt[c * 448 + 306 + r] = 0;
    } else if (b < 562) {
        int bb = b - 434;
        int side = bb >> 6;
        int o = (bb & 63) * 256 + t;                // < 16384
        int k = o >> 7, c = o & 127;
        const float* W = side ? Wi : Wu;
        unsigned short* Bpt = side ? Bpti : Bptu;
        Bpt[c * 128 + k] = (unsigned short)f2bf(W[k * D + c]);
    } else if (b < 564) {
        int side = b - 562;
        unsigned short* Bpt = side ? Bpti : Bptu;
        for (int j = 0; j < 7; ++j)
            Bpt[178 * 128 + t * 7 + j] = 0;
    } else {
        int bb = b - 564;
        int side = bb / 25;
        int ro = (bb % 25) * 2;                     // 2 embk rows per block
        const float* EK = side ? iek : uek;
        const float* G  = side ? gi : gu;
        const float* U  = side ? ui : uu;
        unsigned short* Bt = side ? Bti : Btu;
        int r = t >> 7, c = t & 127;
        float a = 0.f;
        for (int k = 0; k < D; ++k) a += EK[(ro + r) * D + k] * G[k * D + c];
        T[r][c] = a;
        __syncthreads();
        float e = 0.f;
        for (int j = 0; j < D; ++j) e += T[r][j] * U[j * D + c];
        Bt[c * 448 + 256 + ro + r] = (unsigned short)f2bf(e);
    }
}

// ---------------------------------------------------------------------------
// proj_mfma — unchanged.
// ---------------------------------------------------------------------------
__global__ __launch_bounds__(256) void proj_mfma(
    const float* __restrict__ Xu, const float* __restrict__ Xi,
    const unsigned* __restrict__ Bptu32, const unsigned* __restrict__ Bpti32,
    unsigned* __restrict__ h32, float* __restrict__ eproj,
    unsigned* __restrict__ A32, int NU)
{
    __shared__ __align__(16) unsigned Bs[192 * 68];     // 52 KB
    int t = threadIdx.x;
    int nb = blockIdx.x * 32;
    const float* X = (nb < NU) ? Xu : Xi;
    int xoff = (nb < NU) ? 0 : NU;
    const unsigned* Bt = (nb < NU) ? Bptu32 : Bpti32;   // [192][64 u32]
    int wave = t >> 6, lane = t & 63;
    int m16 = lane & 15, quad = lane >> 4;

    #pragma unroll
    for (int i = 0; i < 12; ++i) {                      // 3072 uint4
        int idx = t + i * 256;
        int c = idx >> 4, q = idx & 15;
        uint4 v = *(const uint4*)&Bt[(size_t)c * 64 + q * 4];
        *(uint4*)&Bs[c * 68 + q * 4] = v;
    }
    __syncthreads();

    f32x4 acc[2][3];
    for (int i = 0; i < 2; ++i)
        for (int j = 0; j < 3; ++j) acc[i][j] = (f32x4){0.f, 0.f, 0.f, 0.f};

    #pragma unroll
    for (int kc = 0; kc < 4; ++kc) {
        FragU a[2];
        #pragma unroll
        for (int mi = 0; mi < 2; ++mi) {
            int row = nb + mi * 16 + m16;
            const float* src = &X[(size_t)(row - xoff) * D + kc * 32 + quad * 8];
            float4 v0 = *(const float4*)&src[0];
            float4 v1 = *(const float4*)&src[4];
            uint4 pk;
            pk.x = f2bf(v0.x) | (f2bf(v0.y) << 16);
            pk.y = f2bf(v0.z) | (f2bf(v0.w) << 16);
            pk.z = f2bf(v1.x) | (f2bf(v1.y) << 16);
            pk.w = f2bf(v1.z) | (f2bf(v1.w) << 16);
            a[mi].u4 = pk;
            if (wave == 0)                              // one wave writes x->A32
                *(uint4*)&A32[(size_t)row * 224 + 160 + kc * 16 + quad * 4] = pk;
        }
        #pragma unroll
        for (int ni = 0; ni < 3; ++ni) {
            bf16x8 bb = *(const bf16x8*)&Bs[(wave * 48 + ni * 16 + m16) * 68 + kc * 16 + quad * 4];
            acc[0][ni] = __builtin_amdgcn_mfma_f32_16x16x32_bf16(a[0].f, bb, acc[0][ni], 0, 0, 0);
            acc[1][ni] = __builtin_amdgcn_mfma_f32_16x16x32_bf16(a[1].f, bb, acc[1][ni], 0, 0, 0);
        }
    }
    // epilogue: C/D layout col=lane&15, row=quad*4+r
    #pragma unroll
    for (int mi = 0; mi < 2; ++mi)
        #pragma unroll
        for (int ni = 0; ni < 3; ++ni) {
            int col = wave * 48 + ni * 16 + m16;
            #pragma unroll
            for (int r = 0; r < 4; ++r) {
                float me = acc[mi][ni][r];
                float pr = __shfl_xor(me, 1);           // partner col (lane^1)
                int row = nb + mi * 16 + quad * 4 + r;
                if (col < 128) {
                    if (!(lane & 1))
                        h32[(size_t)row * 64 + (col >> 1)] = f2bf(me) | (f2bf(pr) << 16);
                } else if (col < 178) {
                    eproj[(size_t)row * L + (col - 128)] = me;
                }
            }
        }
}

// ---------------------------------------------------------------------------
// agg v4 — R7 structure; three wave0-critical-path cuts:
//   (1) int4-vectorized rank loop (verified logic from R3),
//   (2) eproj prefetched in-register right after rank (hides ~500cy global
//       latency under stage+scores; index is thread-local),
//   (3) weighted-sum loop fully unrolled, 2x2 accumulators (immediate-offset
//       ds_reads, halved FMA dep chain).
// ---------------------------------------------------------------------------
__global__ __launch_bounds__(256) void agg_kernel(
    const unsigned* __restrict__ h32, const float* __restrict__ eproj,
    const int* __restrict__ unbr, const int* __restrict__ untime,
    const int* __restrict__ inbr, const int* __restrict__ intime,
    unsigned* __restrict__ A32, int NU, int NI)
{
    __shared__ unsigned smail[2][L * 66];     // bf16x2, stride 66 u32
    __shared__ unsigned shb[2][64];           // h packed bf16
    __shared__ float se2[2][2][64];           // [long/short][slot]
    __shared__ float salpha[2][L], salpha1[2][L];
    __shared__ __align__(16) int stime[2][52];
    __shared__ int sreorder[2][L], snbr[2][L], slast[2];

    int tb = threadIdx.x;
    int sub = tb >> 7;                  // node slot 0/1
    int t = tb & 127;                   // within-node tid
    int g = blockIdx.x * 2 + sub;       // global node
    int wave = t >> 6, lane = t & 63;
    int m16 = lane & 15, quad = lane >> 4;

    const unsigned* mail; const int* nbrp; const int* timp;
    if (g < NU) { mail = h32 + (size_t)NU * 64; nbrp = unbr + (size_t)g * L;        timp = untime + (size_t)g * L; }
    else        { mail = h32;                   nbrp = inbr + (size_t)(g - NU) * L; timp = intime + (size_t)(g - NU) * L; }

    if (t < 64) shb[sub][t] = h32[(size_t)g * 64 + t];
    if (t < L) { stime[sub][t] = timp[t]; snbr[sub][t] = nbrp[t]; }
    __syncthreads();

    // ranks (stable argsort∘argsort) + first-occurrence argmax, int4-vector
    float epv = 0.f;
    if (t < L) {
        int ti = stime[sub][t];
        int rank = 0, bad = 0;          // bad: exists j beating t for argmax
        #pragma unroll
        for (int j4 = 0; j4 < 48; j4 += 4) {
            int4 v = *(const int4*)&stime[sub][j4];
            int tj;
            tj = v.x; rank += (tj < ti) || (tj == ti && (j4 + 0) < t); bad |= (tj > ti) || (tj == ti && (j4 + 0) < t);
            tj = v.y; rank += (tj < ti) || (tj == ti && (j4 + 1) < t); bad |= (tj > ti) || (tj == ti && (j4 + 1) < t);
            tj = v.z; rank += (tj < ti) || (tj == ti && (j4 + 2) < t); bad |= (tj > ti) || (tj == ti && (j4 + 2) < t);
            tj = v.w; rank += (tj < ti) || (tj == ti && (j4 + 3) < t); bad |= (tj > ti) || (tj == ti && (j4 + 3) < t);
        }
        {
            int2 v = *(const int2*)&stime[sub][48];
            int tj;
            tj = v.x; rank += (tj < ti) || (tj == ti && 48 < t); bad |= (tj > ti) || (tj == ti && 48 < t);
            tj = v.y; rank += (tj < ti) || (tj == ti && 49 < t); bad |= (tj > ti) || (tj == ti && 49 < t);
        }
        int reo = L - 1 - rank;
        sreorder[sub][t] = reo;
        if (!bad) slast[sub] = t;
        // prefetch eproj for softmax (same thread consumes it: wave0, lane==t)
        epv = eproj[(size_t)g * L + reo];
    }
    // stage mail: uint2 global copy -> LDS stride 66 (no convert)
    {
        int q = t >> 5, p = t & 31;     // row group, pair index
        #pragma unroll
        for (int i = 0; i < 13; ++i) {
            int l = i * 4 + q;
            if (l < L) {
                uint2 v = *(const uint2*)&mail[(size_t)snbr[sub][l] * 64 + p * 2];
                *(uint2*)&smail[sub][l * 66 + 2 * p] = v;
            }
        }
    }
    __syncthreads();

    // scores via MFMA: col0 = mail.h (long), col1 = mail.last
    {
        const unsigned* bptr = (m16 == 1) ? &smail[sub][slast[sub] * 66]
                                          : &shb[sub][0];
        int s0 = wave * 32 + m16;  if (s0 > 49) s0 = 49;
        int s1 = wave * 32 + 16 + m16;  if (s1 > 49) s1 = 49;
        const unsigned* a0p = &smail[sub][s0 * 66];
        const unsigned* a1p = &smail[sub][s1 * 66];
        f32x4 d0 = {0.f, 0.f, 0.f, 0.f}, d1 = {0.f, 0.f, 0.f, 0.f};
        #pragma unroll
        for (int kc = 0; kc < 4; ++kc) {
            int off = kc * 16 + quad * 4;
            FragU bf_, af0, af1;
            bf_.u2[0] = *(const uint2*)&bptr[off];
            bf_.u2[1] = *(const uint2*)&bptr[off + 2];
            af0.u2[0] = *(const uint2*)&a0p[off];
            af0.u2[1] = *(const uint2*)&a0p[off + 2];
            af1.u2[0] = *(const uint2*)&a1p[off];
            af1.u2[1] = *(const uint2*)&a1p[off + 2];
            d0 = __builtin_amdgcn_mfma_f32_16x16x32_bf16(af0.f, bf_.f, d0, 0, 0, 0);
            d1 = __builtin_amdgcn_mfma_f32_16x16x32_bf16(af1.f, bf_.f, d1, 0, 0, 0);
        }
        if (m16 < 2) {                   // redistribute: row=quad*4+r, col=m16
            #pragma unroll
            for (int r = 0; r < 4; ++r) {
                se2[sub][m16][wave * 32 + quad * 4 + r]      = d0[r];
                se2[sub][m16][wave * 32 + 16 + quad * 4 + r] = d1[r];
            }
        }
    }
    __syncthreads();

    // softmax: wave0 long (+prefetched eproj), wave1 short
    float sc = -1e30f;
    if (lane < L) {
        sc = (wave == 0)
           ? (se2[sub][0][lane] + epv) * SCALE
           : se2[sub][1][lane] * SCALE;
    }
    float mx = sc;
    for (int off = 32; off; off >>= 1) mx = fmaxf(mx, __shfl_xor(mx, off));
    float ex = (lane < L) ? expf(sc - mx) : 0.f;
    float sm = ex;
    for (int off = 32; off; off >>= 1) sm += __shfl_xor(sm, off);
    float al = ex / sm;
    if (lane < L) { if (wave == 0) salpha[sub][lane] = al; else salpha1[sub][lane] = al; }
    __syncthreads();

    // weighted sums: wave0 -> hl word lane, wave1 -> hs word lane
    // fully unrolled, 2x2 accumulators (dep-chain halved, imm-offset reads)
    {
        const float* alp = wave ? salpha1[sub] : salpha[sub];
        const unsigned* base = &smail[sub][lane];
        float ax0 = 0.f, ay0 = 0.f, ax1 = 0.f, ay1 = 0.f;
        #pragma unroll
        for (int l = 0; l < L; l += 2) {
            unsigned u0 = base[l * 66];
            unsigned u1 = base[(l + 1) * 66];
            float a0 = alp[l];
            float a1 = alp[l + 1];
            ax0 += a0 * bflo(u0);
            ay0 += a0 * bfhi(u0);
            ax1 += a1 * bflo(u1);
            ay1 += a1 * bfhi(u1);
        }
        float ax = ax0 + ax1, ay = ay0 + ay1;
        A32[(size_t)g * 224 + wave * 64 + lane] = f2bf(ax) | (f2bf(ay) << 16);
    }
    if (t >= 64 && t < 96) A32[(size_t)g * 224 + 128 + (t - 64)] = 0u;
    __syncthreads();
    if (t < L) {
        ((unsigned short*)A32)[(size_t)g * 448 + 256 + sreorder[sub][t]] =
            (unsigned short)f2bf(salpha[sub][t]);
    }
}

// ---------------------------------------------------------------------------
// gemm_out v2 (reverted to R0 64-col halves — best measured config).
// ---------------------------------------------------------------------------
__global__ __launch_bounds__(256) void gemm_out_mfma(
    const unsigned* __restrict__ A32,
    const unsigned* __restrict__ Btu32, const unsigned* __restrict__ Bti32,
    float* __restrict__ out, int NU)
{
    __shared__ __align__(16) unsigned Bs[64 * 228];     // 57 KB
    int t = threadIdx.x;
    int rowblk = blockIdx.x >> 1, half = blockIdx.x & 1;
    int nb = rowblk * 128;
    const unsigned* Bt = (nb < NU) ? Btu32 : Bti32;     // [128 n][224 u32]
    int wave = t >> 6, lane = t & 63;
    int m16 = lane & 15, quad = lane >> 4;

    #pragma unroll
    for (int i = 0; i < 14; ++i) {                      // 3584 uint4
        int idx = t + i * 256;
        int n = idx / 56, q = idx - n * 56;             // 56 uint4 per row
        uint4 v = *(const uint4*)&Bt[(size_t)(half * 64 + n) * 224 + q * 4];
        *(uint4*)&Bs[n * 228 + q * 4] = v;
    }
    __syncthreads();

    #pragma unroll
    for (int j = 0; j < 2; ++j) {
        int mrow0 = nb + (wave * 2 + j) * 16;
        f32x4 acc[4] = {{0.f,0.f,0.f,0.f},{0.f,0.f,0.f,0.f},
                        {0.f,0.f,0.f,0.f},{0.f,0.f,0.f,0.f}};
        for (int kc = 0; kc < 14; ++kc) {
            FragU af;
            af.u4 = *(const uint4*)&A32[(size_t)(mrow0 + m16) * 224 + kc * 16 + quad * 4];
            #pragma unroll
            for (int ni = 0; ni < 4; ++ni) {
                bf16x8 bf = *(const bf16x8*)&Bs[(ni * 16 + m16) * 228 + kc * 16 + quad * 4];
                acc[ni] = __builtin_amdgcn_mfma_f32_16x16x32_bf16(af.f, bf, acc[ni], 0, 0, 0);
            }
        }
        #pragma unroll
        for (int ni = 0; ni < 4; ++ni)
            #pragma unroll
            for (int r = 0; r < 4; ++r) {
                int row = mrow0 + quad * 4 + r;
                int col = half * 64 + ni * 16 + m16;
                out[(size_t)row * D + col] = tanhf(acc[ni][r]);
            }
    }
}

// ---------------------------------------------------------------------------
extern "C" void kernel_launch(void* const* d_in, const int* in_sizes, int n_in,
                              void* d_out, int out_size, void* d_ws, size_t ws_size,
                              hipStream_t stream) {
    const float* user   = (const float*)d_in[0];
    const float* item   = (const float*)d_in[1];
    const float* Wu     = (const float*)d_in[2];
    const float* Wi     = (const float*)d_in[3];
    const float* gate_u = (const float*)d_in[4];
    const float* gate_i = (const float*)d_in[5];
    const float* upd_u  = (const float*)d_in[6];
    const float* upd_i  = (const float*)d_in[7];
    const float* uemb   = (const float*)d_in[8];
    const float* uembk  = (const float*)d_in[9];
    const float* iemb   = (const float*)d_in[10];
    const float* iembk  = (const float*)d_in[11];
    const int*   unbr   = (const int*)d_in[12];
    const int*   untime = (const int*)d_in[13];
    const int*   inbr   = (const int*)d_in[14];
    const int*   intime = (const int*)d_in[15];

    int NU = in_sizes[0] / D;
    int NI = in_sizes[1] / D;
    int N  = NU + NI;

    float* eproj  = (float*)d_ws;                   // N*50 f32
    unsigned* h32   = (unsigned*)(eproj + (size_t)N * L);  // N*64 u32
    unsigned* A32   = h32 + (size_t)N * 64;         // N*224 u32 (bf16 A)
    unsigned* Btu32 = A32 + (size_t)N * 224;        // 128*224 u32 each
    unsigned* Bti32 = Btu32 + 128 * 224;
    unsigned* Bptu32 = Bti32 + 128 * 224;           // 192*64 u32 each
    unsigned* Bpti32 = Bptu32 + 192 * 64;

    prep_all_kernel<<<614, 256, 0, stream>>>(Wu, Wi, uemb, iemb, gate_u, gate_i,
                                             upd_u, upd_i, uembk, iembk,
                                             (unsigned short*)Bptu32,
                                             (unsigned short*)Bpti32,
                                             (unsigned short*)Btu32,
                                             (unsigned short*)Bti32);
    proj_mfma<<<N / 32, 256, 0, stream>>>(user, item, Bptu32, Bpti32,
                                          h32, eproj, A32, NU);
    agg_kernel<<<N / 2, 256, 0, stream>>>(h32, eproj, unbr, untime, inbr,
                                          intime, A32, NU, NI);
    gemm_out_mfma<<<N / 64, 256, 0, stream>>>(A32, Btu32, Bti32,
                                              (float*)d_out, NU);
}